// Round 3
// baseline (1295.242 us; speedup 1.0000x reference)
//
#include <hip/hip_runtime.h>
#include <hip/hip_bf16.h>
#include <math.h>

#define B_N 16384
#define K_N 20
#define D_N 256
#define H_N 4

typedef __attribute__((ext_vector_type(8))) short v8s;
typedef __attribute__((ext_vector_type(4))) float v4f;
typedef __hip_bfloat16 bf16;

static __device__ __forceinline__ float bf2f(bf16 x){ return __bfloat162float(x); }
static __device__ __forceinline__ bf16 f2bf(float x){ return __float2bfloat16(x); }
static __device__ __forceinline__ float bfb2f(short s){ bf16 v; *(short*)&v = s; return __bfloat162float(v); }
static __device__ __forceinline__ short bfbits(float x){ bf16 v = __float2bfloat16(x); return *(short*)&v; }

// ---------------------------------------------------------------- prep ------
// casts weights to bf16, builds Wcat=[ad_w1; wq; imp_w1a], catb, g_h, qc, wkT,
// w1b (imp_w1[:,256:512]), and nm_bf16. Flat concatenated index space.
__global__ __launch_bounds__(256) void k_prep(
    const float* __restrict__ ad_w1, const float* __restrict__ ad_b1,
    const float* __restrict__ imp_w1, const float* __restrict__ imp_b1,
    const float* __restrict__ attn_in_w, const float* __restrict__ attn_in_b,
    const float* __restrict__ attn_out_w, const float* __restrict__ nm,
    bf16* __restrict__ attn_bf, bf16* __restrict__ w1b, bf16* __restrict__ wout_bf,
    bf16* __restrict__ wcat, float* __restrict__ catb,
    float* __restrict__ g, float* __restrict__ qc,
    bf16* __restrict__ wkT, bf16* __restrict__ nm_bf)
{
    long o = (long)blockIdx.x * 256 + threadIdx.x;
    const long n_attn = 768*256, n_w1b = 65536, n_wout = 256*256, n_wcat = 640*256;
    const long n_catb = 640, n_g = 1024, n_qc = 4, n_wkT = 1024*64, n_nm = (long)B_N*256;
    if (o < n_attn){ attn_bf[o] = f2bf(attn_in_w[o]); return; } o -= n_attn;
    if (o < n_w1b){ // w1b[j][k] = imp_w1[j][256+k]
        int j = (int)(o >> 8), k = (int)(o & 255);
        w1b[o] = f2bf(imp_w1[j*512 + 256 + k]); return; } o -= n_w1b;
    if (o < n_wout){ wout_bf[o] = f2bf(attn_out_w[o]); return; } o -= n_wout;
    if (o < n_wcat){
        int r = (int)(o >> 8), c = (int)(o & 255); float v;
        if (r < 128)      v = ad_w1[r*256 + c];
        else if (r < 384) v = attn_in_w[(r-128)*256 + c];       // wq rows
        else              v = imp_w1[(r-384)*512 + c];          // imp_w1[:, :256]
        wcat[o] = f2bf(v); return; } o -= n_wcat;
    if (o < n_catb){
        int r = (int)o; float v;
        if (r < 128) v = ad_b1[r]; else if (r < 384) v = attn_in_b[r-128]; else v = imp_b1[r-384];
        catb[r] = v; return; } o -= n_catb;
    if (o < n_g){   // g[h][d] = sum_i wq[h*64+i][d] * bk[h*64+i]
        int h = (int)(o >> 8), d = (int)(o & 255); float s = 0.f;
        for (int j = 0; j < 64; ++j) s += attn_in_w[(h*64+j)*256 + d] * attn_in_b[256 + h*64 + j];
        g[o] = s; return; } o -= n_g;
    if (o < n_qc){  // qc[h] = bq_h . bk_h
        int h = (int)o; float s = 0.f;
        for (int j = 0; j < 64; ++j) s += attn_in_b[h*64+j] * attn_in_b[256 + h*64 + j];
        qc[h] = s; return; } o -= n_qc;
    if (o < n_wkT){ // wkT[c][i] = wk[head(c)*64+i][d(c)],  c = h*256+d
        int c = (int)(o >> 6), i = (int)(o & 63);
        int h = c >> 8, d = c & 255;
        wkT[o] = f2bf(attn_in_w[(256 + h*64 + i)*256 + d]); return; } o -= n_wkT;
    if (o < n_nm){ nm_bf[o] = f2bf(nm[o]); return; }
}

// ---------------------------------------------------------------- gemm ------
// C[b][n] = epi( sum_k X[b][aoff+k] * W[n][k] + bias[n] + csrc[b][n] )
// 16x16x32 bf16 MFMA, block = 4 waves = 64 rows x 64 cols tile, no LDS.
__global__ __launch_bounds__(256) void k_gemm(
    const bf16* __restrict__ X, int ldx, int agshift, int agstride,
    const bf16* __restrict__ W, int ldw,
    const float* __restrict__ bias,
    const bf16* __restrict__ csrc, int ldc,
    void* __restrict__ outp, int ldo, int out_bf16,
    int relu_hi, int Kd)
{
    int wave = threadIdx.x >> 6, lane = threadIdx.x & 63;
    int l15 = lane & 15, koct = lane >> 4;
    int rblk = blockIdx.x * 64 + wave * 16;
    int cb = blockIdx.y * 64;
    long arow = rblk + l15;
    long aoff = (long)(cb >> agshift) * agstride;
    const bf16* Xp = X + arow * ldx + aoff + koct * 8;
    v4f acc[4];
    #pragma unroll
    for (int ct = 0; ct < 4; ++ct) acc[ct] = (v4f){0.f,0.f,0.f,0.f};
    for (int k0 = 0; k0 < Kd; k0 += 32){
        v8s a = *(const v8s*)(Xp + k0);
        #pragma unroll
        for (int ct = 0; ct < 4; ++ct){
            const bf16* Wp = W + (long)(cb + ct*16 + l15) * ldw + k0 + koct * 8;
            v8s bb = *(const v8s*)Wp;
            acc[ct] = __builtin_amdgcn_mfma_f32_16x16x32_bf16(a, bb, acc[ct], 0, 0, 0);
        }
    }
    int orow_base = rblk + koct * 4;   // C/D: row = (lane>>4)*4 + reg, col = lane&15
    #pragma unroll
    for (int ct = 0; ct < 4; ++ct){
        int ocol = cb + ct*16 + l15;
        float bv = bias ? bias[ocol] : 0.0f;
        #pragma unroll
        for (int r = 0; r < 4; ++r){
            long orow = orow_base + r;
            float v = acc[ct][r] + bv;
            if (csrc) v += bf2f(csrc[orow * ldc + ocol]);
            if (ocol < relu_hi) v = fmaxf(v, 0.0f);
            if (out_bf16) ((bf16*)outp)[orow * ldo + ocol] = f2bf(v);
            else          ((float*)outp)[orow * ldo + ocol] = v;
        }
    }
}

// ---------------------------------------------------------------- fused -----
// one block per batch. Single pass over storage (all 20 rows) computing:
//   stats (mask, mean, std, z-count)  -> stat_anom   [was k_stats]
//   learned anomaly dot on cat1[0:128]               [was k_learned]
//   t = relu(pre1a + hmean @ W1b^T), imp dot          [was GEMM-6 + k_imp]
//   attention scores / softmax / u, st write          [was k_attn]
// st rows 1..19 stream out during staging (overlaps everything downstream).
__global__ __launch_bounds__(256) void k_fused(
    const float* __restrict__ storage, const float* __restrict__ nm,
    const bf16* __restrict__ R_bf, const bf16* __restrict__ cat1,
    const bf16* __restrict__ w1b,
    const float* __restrict__ ad_w2, const float* __restrict__ ad_b2,
    const float* __restrict__ imp_w2, const float* __restrict__ imp_b2,
    const float* __restrict__ g, const float* __restrict__ qc,
    float* __restrict__ st_out, bf16* __restrict__ u_bf)
{
    __shared__ float4 stor4[K_N * 64];          // 20 rows x 64 float4 = 20480 B
    __shared__ float nm_s[D_N];
    __shared__ float mu_s[D_N];
    __shared__ float mask_s[K_N];
    __shared__ int   zc_s[H_N];
    __shared__ float red_s[2*H_N];              // [0..3] imp partials, [4..7] learned
    int b = blockIdx.x, t = threadIdx.x, h = t >> 6, lane = t & 63;
    const float4* S4 = (const float4*)(storage + (long)b * K_N * D_N);
    float4*       O4 = (float4*)(st_out + (long)b * K_N * D_N);

    float4 nm4 = ((const float4*)(nm + (long)b * D_N))[lane];
    short4 r4  = ((const short4*)(R_bf + (long)b * (H_N*D_N) + h * D_N))[lane];
    float4 R4;
    R4.x = bfb2f(r4.x); R4.y = bfb2f(r4.y); R4.z = bfb2f(r4.z); R4.w = bfb2f(r4.w);
    float4 g4 = ((const float4*)(g + h * D_N))[lane];
    float qch = qc[h];

    // ---- staging: 20 rows, row mask via ballot, fused st rows 1..19 --------
    float4 vv[5];
    #pragma unroll
    for (int j = 0; j < 5; ++j) vv[j] = S4[t + j*256];   // row = h + 4j, col = lane
    if (h == 0) ((float4*)nm_s)[lane] = nm4;
    {
        float dd = 1.0f;
        #pragma unroll
        for (int j = 0; j < 3; ++j) if (j < h) dd *= 0.95f;   // 0.95^h
        const float step = 0.81450625f;                       // 0.95^4
        #pragma unroll
        for (int j = 0; j < 5; ++j){
            int i = t + j*256;
            int row = h + 4*j;
            stor4[i] = vv[j];
            bool nz = (vv[j].x != 0.f) || (vv[j].y != 0.f) || (vv[j].z != 0.f) || (vv[j].w != 0.f);
            unsigned long long bal = __ballot(nz);
            if (lane == 0) mask_s[row] = (bal != 0ULL) ? 1.0f : 0.0f;
            if (row < K_N-1){                      // st row (row+1) = storage[row]*0.95^row
                float4 o;
                o.x = vv[j].x * dd; o.y = vv[j].y * dd;
                o.z = vv[j].z * dd; o.w = vv[j].w * dd;
                O4[i + 64] = o;
            }
            dd *= step;
        }
    }
    __syncthreads();

    // ---- column stats: thread t = column d ---------------------------------
    {
        const float* S = (const float*)stor4;
        float cm = 0.f, s1 = 0.f, s2 = 0.f;
        #pragma unroll
        for (int k = 0; k < K_N; ++k){
            float m = mask_s[k];
            float x = S[k*D_N + t];
            cm += m; s1 += m*x; s2 += m*x*x;
        }
        float denom = cm + 1e-8f;
        float mu = s1 / denom;
        float var = (s2 - 2.0f*mu*s1 + mu*mu*cm) / denom;
        float sd = sqrtf(fmaxf(var, 0.0f));
        mu_s[t] = mu;
        float z = fabsf((nm_s[t] - mu) / (sd + 1e-8f));
        unsigned long long bal = __ballot(z > 2.0f);
        if (lane == 0) zc_s[h] = __popcll(bal);
    }
    __syncthreads();

    // ---- t[j] = relu(pre1a[j] + mu . W1b[j]);  imp & learned partials ------
    {
        float acc = bf2f(cat1[(long)b*640 + 384 + t]);       // pre1a (incl imp_b1)
        const v8s* wrow = (const v8s*)(w1b + (long)t * 256);
        const float4* mu4 = (const float4*)mu_s;
        #pragma unroll
        for (int c = 0; c < 32; ++c){
            v8s wv8 = wrow[c];
            float4 ma = mu4[2*c], mb = mu4[2*c+1];
            acc += ma.x*bfb2f(wv8[0]) + ma.y*bfb2f(wv8[1]) + ma.z*bfb2f(wv8[2]) + ma.w*bfb2f(wv8[3])
                 + mb.x*bfb2f(wv8[4]) + mb.y*bfb2f(wv8[5]) + mb.z*bfb2f(wv8[6]) + mb.w*bfb2f(wv8[7]);
        }
        float tj = fmaxf(acc, 0.0f);
        float pi = tj * imp_w2[t];
        float pl = (t < 128) ? bf2f(cat1[(long)b*640 + t]) * ad_w2[t] : 0.0f;
        #pragma unroll
        for (int s = 32; s; s >>= 1){ pi += __shfl_xor(pi, s); pl += __shfl_xor(pl, s); }
        if (lane == 0){ red_s[h] = pi; red_s[H_N + h] = pl; }
    }
    __syncthreads();

    float impv;
    {
        float p  = red_s[0]+red_s[1]+red_s[2]+red_s[3] + imp_b2[0];
        float plr= red_s[4]+red_s[5]+red_s[6]+red_s[7] + ad_b2[0];
        float learned = 1.0f / (1.0f + expf(-plr));
        float stat = (float)(zc_s[0]+zc_s[1]+zc_s[2]+zc_s[3]) * (1.0f/256.0f);
        float sp = (p > 20.0f) ? p : log1pf(expf(p));
        impv = sp * (1.0f + 0.5f*stat + 0.5f*learned);
    }
    if (h == 0){                              // st row 0 = imp * nm
        float4 o;
        o.x = impv * nm4.x; o.y = impv * nm4.y;
        o.z = impv * nm4.z; o.w = impv * nm4.w;
        O4[lane] = o;
    }

    // ---- scores: 21 partials, one batched shuffle reduce -------------------
    const int NP = K_N + 1;                   // [0]=nm.g, [1]=nm.R, [2+k]=row k.R
    float p[NP];
    p[0] = nm4.x*g4.x + nm4.y*g4.y + nm4.z*g4.z + nm4.w*g4.w;
    p[1] = nm4.x*R4.x + nm4.y*R4.y + nm4.z*R4.z + nm4.w*R4.w;
    #pragma unroll
    for (int k = 0; k < K_N-1; ++k){
        float4 x = stor4[k*64 + lane];
        p[2+k] = x.x*R4.x + x.y*R4.y + x.z*R4.z + x.w*R4.w;
    }
    #pragma unroll
    for (int s = 32; s; s >>= 1){
        #pragma unroll
        for (int j = 0; j < NP; ++j) p[j] += __shfl_xor(p[j], s);
    }
    float dec[K_N-1];
    dec[0] = 1.0f;
    #pragma unroll
    for (int k = 1; k < K_N-1; ++k) dec[k] = dec[k-1] * 0.95f;
    float qb = p[0] + qch;
    float sc[K_N];
    sc[0] = (impv * p[1] + qb) * 0.125f;
    #pragma unroll
    for (int k = 0; k < K_N-1; ++k) sc[k+1] = (dec[k] * p[2+k] + qb) * 0.125f;
    float mx = sc[0];
    #pragma unroll
    for (int k = 1; k < K_N; ++k) mx = fmaxf(mx, sc[k]);
    float l = 0.f, w[K_N];
    #pragma unroll
    for (int k = 0; k < K_N; ++k){ w[k] = expf(sc[k]-mx); l += w[k]; }
    float inv = 1.0f / l;
    float w0 = w[0] * inv * impv;
    float cw[K_N-1];
    #pragma unroll
    for (int k = 0; k < K_N-1; ++k) cw[k] = w[k+1] * inv * dec[k];

    // ---- u = w0*nm + sum_k cw[k]*storage[k], packed bf16x4 write -----------
    float4 acc;
    acc.x = w0 * nm4.x; acc.y = w0 * nm4.y; acc.z = w0 * nm4.z; acc.w = w0 * nm4.w;
    #pragma unroll
    for (int k = 0; k < K_N-1; ++k){
        float4 x = stor4[k*64 + lane];
        acc.x += cw[k]*x.x; acc.y += cw[k]*x.y; acc.z += cw[k]*x.z; acc.w += cw[k]*x.w;
    }
    short4 us;
    us.x = bfbits(acc.x); us.y = bfbits(acc.y); us.z = bfbits(acc.z); us.w = bfbits(acc.w);
    ((short4*)(u_bf + (long)b * (H_N*D_N) + h * D_N))[lane] = us;
}

// ---------------------------------------------------------------- launch ----
extern "C" void kernel_launch(void* const* d_in, const int* in_sizes, int n_in,
                              void* d_out, int out_size, void* d_ws, size_t ws_size,
                              hipStream_t stream)
{
    (void)in_sizes; (void)n_in; (void)out_size; (void)ws_size;
    const float* storage    = (const float*)d_in[0];
    const float* nm         = (const float*)d_in[1];
    const float* ad_w1      = (const float*)d_in[2];
    const float* ad_b1      = (const float*)d_in[3];
    const float* ad_w2      = (const float*)d_in[4];
    const float* ad_b2      = (const float*)d_in[5];
    const float* imp_w1     = (const float*)d_in[6];
    const float* imp_b1     = (const float*)d_in[7];
    const float* imp_w2     = (const float*)d_in[8];
    const float* imp_b2     = (const float*)d_in[9];
    const float* attn_in_w  = (const float*)d_in[10];
    const float* attn_in_b  = (const float*)d_in[11];
    const float* attn_out_w = (const float*)d_in[12];
    const float* attn_out_b = (const float*)d_in[13];

    char* p = (char*)d_ws;
    auto alloc = [&](size_t bytes)->char*{ char* r = p; p += (bytes + 255) & ~(size_t)255; return r; };
    bf16*  attn_bf   = (bf16*) alloc((size_t)768*256*2);
    bf16*  w1b       = (bf16*) alloc((size_t)256*256*2);
    bf16*  wout_bf   = (bf16*) alloc((size_t)256*256*2);
    bf16*  wcat      = (bf16*) alloc((size_t)640*256*2);
    float* catb      = (float*)alloc((size_t)640*4);
    float* g         = (float*)alloc((size_t)1024*4);
    float* qc        = (float*)alloc((size_t)4*4);
    bf16*  wkT       = (bf16*) alloc((size_t)1024*64*2);
    bf16*  nm_bf     = (bf16*) alloc((size_t)B_N*256*2);
    bf16*  cat1      = (bf16*) alloc((size_t)B_N*640*2);
    bf16*  R_bf      = (bf16*) alloc((size_t)B_N*1024*2);
    bf16*  u_bf      = (bf16*) alloc((size_t)B_N*1024*2);
    bf16*  ctx_bf    = (bf16*) alloc((size_t)B_N*256*2);

    float* st_out  = (float*)d_out;
    float* agg_out = (float*)d_out + (size_t)B_N * K_N * D_N;

    // 1. prep
    {
        long total = 768*256 + 65536 + 256*256 + 640*256 + 640 + 1024 + 4 + 1024*64 + (long)B_N*256;
        int grid = (int)((total + 255) / 256);
        k_prep<<<grid, 256, 0, stream>>>(ad_w1, ad_b1, imp_w1, imp_b1, attn_in_w, attn_in_b,
                                         attn_out_w, nm, attn_bf, w1b, wout_bf, wcat, catb,
                                         g, qc, wkT, nm_bf);
    }
    // 2. fused nm GEMM: cols [0,128)=relu(ad) | [128,384)=q+bq | [384,640)=pre1a+imp_b1
    k_gemm<<<dim3(B_N/64, 640/64), 256, 0, stream>>>(nm_bf, 256, 30, 0, wcat, 256, catb,
        (const bf16*)nullptr, 0, cat1, 640, 1, 128, 256);
    // 3. R = q_h @ wk_h  (K=64, per-head A offset, wkT rows contiguous in k)
    k_gemm<<<dim3(B_N/64, 1024/64), 256, 0, stream>>>(cat1 + 128, 640, 8, 64, wkT, 64,
        (const float*)nullptr, (const bf16*)nullptr, 0, R_bf, 1024, 1, 0, 64);
    // 4. fused stats + anomaly + importance + attention + st/u write
    k_fused<<<B_N, 256, 0, stream>>>(storage, nm, R_bf, cat1, w1b,
        ad_w2, ad_b2, imp_w2, imp_b2, g, qc, st_out, u_bf);
    // 5. ctx_head = u_head @ wv^T + bv   (per-64-col A group)
    k_gemm<<<dim3(B_N/64, 256/64), 256, 0, stream>>>(u_bf, 1024, 6, 256, attn_bf + 512*256, 256,
        attn_in_b + 512, (const bf16*)nullptr, 0, ctx_bf, 256, 1, 0, 256);
    // 6. agg = ctx @ Wout^T + bout  (fp32 out)
    k_gemm<<<dim3(B_N/64, 256/64), 256, 0, stream>>>(ctx_bf, 256, 30, 0, wout_bf, 256,
        attn_out_b, (const bf16*)nullptr, 0, agg_out, 256, 0, 0, 256);
}

// Round 4
// 874.773 us; speedup vs baseline: 1.4807x; 1.4807x over previous
//
#include <hip/hip_runtime.h>
#include <hip/hip_bf16.h>
#include <math.h>

#define B_N 16384
#define K_N 20
#define D_N 256
#define H_N 4

typedef __attribute__((ext_vector_type(8))) short v8s;
typedef __attribute__((ext_vector_type(4))) float v4f;
typedef __hip_bfloat16 bf16;

static __device__ __forceinline__ float bf2f(bf16 x){ return __bfloat162float(x); }
static __device__ __forceinline__ bf16 f2bf(float x){ return __float2bfloat16(x); }
static __device__ __forceinline__ float bfb2f(short s){ bf16 v; *(short*)&v = s; return __bfloat162float(v); }
static __device__ __forceinline__ short bfbits(float x){ bf16 v = __float2bfloat16(x); return *(short*)&v; }

// ---------------------------------------------------------------- prep ------
// casts weights to bf16, builds Wcat=[ad_w1; wq; imp_w1a], catb, g_h, qc, wkT,
// w1bT (TRANSPOSED imp_w1[:,256:512] -> [k][j]), and nm_bf16.
__global__ __launch_bounds__(256) void k_prep(
    const float* __restrict__ ad_w1, const float* __restrict__ ad_b1,
    const float* __restrict__ imp_w1, const float* __restrict__ imp_b1,
    const float* __restrict__ attn_in_w, const float* __restrict__ attn_in_b,
    const float* __restrict__ attn_out_w, const float* __restrict__ nm,
    bf16* __restrict__ attn_bf, bf16* __restrict__ w1bT, bf16* __restrict__ wout_bf,
    bf16* __restrict__ wcat, float* __restrict__ catb,
    float* __restrict__ g, float* __restrict__ qc,
    bf16* __restrict__ wkT, bf16* __restrict__ nm_bf)
{
    long o = (long)blockIdx.x * 256 + threadIdx.x;
    const long n_attn = 768*256, n_w1b = 65536, n_wout = 256*256, n_wcat = 640*256;
    const long n_catb = 640, n_g = 1024, n_qc = 4, n_wkT = 1024*64, n_nm = (long)B_N*256;
    if (o < n_attn){ attn_bf[o] = f2bf(attn_in_w[o]); return; } o -= n_attn;
    if (o < n_w1b){ // w1bT[k][j] = imp_w1[j][256+k]  (transposed for coalesced matvec)
        int k = (int)(o >> 8), j = (int)(o & 255);
        w1bT[o] = f2bf(imp_w1[j*512 + 256 + k]); return; } o -= n_w1b;
    if (o < n_wout){ wout_bf[o] = f2bf(attn_out_w[o]); return; } o -= n_wout;
    if (o < n_wcat){
        int r = (int)(o >> 8), c = (int)(o & 255); float v;
        if (r < 128)      v = ad_w1[r*256 + c];
        else if (r < 384) v = attn_in_w[(r-128)*256 + c];       // wq rows
        else              v = imp_w1[(r-384)*512 + c];          // imp_w1[:, :256]
        wcat[o] = f2bf(v); return; } o -= n_wcat;
    if (o < n_catb){
        int r = (int)o; float v;
        if (r < 128) v = ad_b1[r]; else if (r < 384) v = attn_in_b[r-128]; else v = imp_b1[r-384];
        catb[r] = v; return; } o -= n_catb;
    if (o < n_g){   // g[h][d] = sum_i wq[h*64+i][d] * bk[h*64+i]
        int h = (int)(o >> 8), d = (int)(o & 255); float s = 0.f;
        for (int j = 0; j < 64; ++j) s += attn_in_w[(h*64+j)*256 + d] * attn_in_b[256 + h*64 + j];
        g[o] = s; return; } o -= n_g;
    if (o < n_qc){  // qc[h] = bq_h . bk_h
        int h = (int)o; float s = 0.f;
        for (int j = 0; j < 64; ++j) s += attn_in_b[h*64+j] * attn_in_b[256 + h*64 + j];
        qc[h] = s; return; } o -= n_qc;
    if (o < n_wkT){ // wkT[c][i] = wk[head(c)*64+i][d(c)],  c = h*256+d
        int c = (int)(o >> 6), i = (int)(o & 63);
        int h = c >> 8, d = c & 255;
        wkT[o] = f2bf(attn_in_w[(256 + h*64 + i)*256 + d]); return; } o -= n_wkT;
    if (o < n_nm){ nm_bf[o] = f2bf(nm[o]); return; }
}

// ---------------------------------------------------------------- gemm ------
// C[b][n] = epi( sum_k X[b][aoff+k] * W[n][k] + bias[n] + csrc[b][n] )
// 16x16x32 bf16 MFMA, block = 4 waves = 64 rows x 64 cols tile, no LDS.
__global__ __launch_bounds__(256) void k_gemm(
    const bf16* __restrict__ X, int ldx, int agshift, int agstride,
    const bf16* __restrict__ W, int ldw,
    const float* __restrict__ bias,
    const bf16* __restrict__ csrc, int ldc,
    void* __restrict__ outp, int ldo, int out_bf16,
    int relu_hi, int Kd)
{
    int wave = threadIdx.x >> 6, lane = threadIdx.x & 63;
    int l15 = lane & 15, koct = lane >> 4;
    int rblk = blockIdx.x * 64 + wave * 16;
    int cb = blockIdx.y * 64;
    long arow = rblk + l15;
    long aoff = (long)(cb >> agshift) * agstride;
    const bf16* Xp = X + arow * ldx + aoff + koct * 8;
    v4f acc[4];
    #pragma unroll
    for (int ct = 0; ct < 4; ++ct) acc[ct] = (v4f){0.f,0.f,0.f,0.f};
    for (int k0 = 0; k0 < Kd; k0 += 32){
        v8s a = *(const v8s*)(Xp + k0);
        #pragma unroll
        for (int ct = 0; ct < 4; ++ct){
            const bf16* Wp = W + (long)(cb + ct*16 + l15) * ldw + k0 + koct * 8;
            v8s bb = *(const v8s*)Wp;
            acc[ct] = __builtin_amdgcn_mfma_f32_16x16x32_bf16(a, bb, acc[ct], 0, 0, 0);
        }
    }
    int orow_base = rblk + koct * 4;   // C/D: row = (lane>>4)*4 + reg, col = lane&15
    #pragma unroll
    for (int ct = 0; ct < 4; ++ct){
        int ocol = cb + ct*16 + l15;
        float bv = bias ? bias[ocol] : 0.0f;
        #pragma unroll
        for (int r = 0; r < 4; ++r){
            long orow = orow_base + r;
            float v = acc[ct][r] + bv;
            if (csrc) v += bf2f(csrc[orow * ldc + ocol]);
            if (ocol < relu_hi) v = fmaxf(v, 0.0f);
            if (out_bf16) ((bf16*)outp)[orow * ldo + ocol] = f2bf(v);
            else          ((float*)outp)[orow * ldo + ocol] = v;
        }
    }
}

// ---------------------------------------------------------------- fused -----
// one block per batch, __launch_bounds__(256,4) -> VGPR<=128, 4 blocks/CU.
// Single storage pass: stats, coalesced wave-k-split matvec (w1bT), anomaly,
// importance, attention, st/u write. st rows 1..19 stream during staging.
__global__ __launch_bounds__(256, 4) void k_fused(
    const float* __restrict__ storage, const float* __restrict__ nm,
    const bf16* __restrict__ R_bf, const bf16* __restrict__ cat1,
    const bf16* __restrict__ w1bT,
    const float* __restrict__ ad_w2, const float* __restrict__ ad_b2,
    const float* __restrict__ imp_w2, const float* __restrict__ imp_b2,
    const float* __restrict__ g, const float* __restrict__ qc,
    float* __restrict__ st_out, bf16* __restrict__ u_bf)
{
    __shared__ float4 stor4[K_N * 64];          // 20 rows x 64 float4 = 20480 B
    __shared__ float nm_s[D_N];
    __shared__ float mu_s[D_N];
    __shared__ float redm[4 * D_N];             // matvec cross-wave partials (4 KB)
    __shared__ float mask_s[K_N];
    __shared__ int   zc_s[H_N];
    __shared__ float red_s[2*H_N];              // [0..3] imp partials, [4..7] learned
    int b = blockIdx.x, t = threadIdx.x, h = t >> 6, lane = t & 63;
    const float4* S4 = (const float4*)(storage + (long)b * K_N * D_N);
    float4*       O4 = (float4*)(st_out + (long)b * K_N * D_N);

    float4 nm4 = ((const float4*)(nm + (long)b * D_N))[lane];

    // ---- staging: 20 rows, row mask via ballot, fused st rows 1..19 --------
    float4 vv[5];
    #pragma unroll
    for (int j = 0; j < 5; ++j) vv[j] = S4[t + j*256];   // row = h + 4j, col = lane
    if (h == 0) ((float4*)nm_s)[lane] = nm4;
    {
        float dd = 1.0f;
        #pragma unroll
        for (int j = 0; j < 3; ++j) if (j < h) dd *= 0.95f;   // 0.95^h
        const float step = 0.81450625f;                       // 0.95^4
        #pragma unroll
        for (int j = 0; j < 5; ++j){
            int i = t + j*256;
            int row = h + 4*j;
            stor4[i] = vv[j];
            bool nz = (vv[j].x != 0.f) || (vv[j].y != 0.f) || (vv[j].z != 0.f) || (vv[j].w != 0.f);
            unsigned long long bal = __ballot(nz);
            if (lane == 0) mask_s[row] = (bal != 0ULL) ? 1.0f : 0.0f;
            if (row < K_N-1){                      // st row (row+1) = storage[row]*0.95^row
                float4 o;
                o.x = vv[j].x * dd; o.y = vv[j].y * dd;
                o.z = vv[j].z * dd; o.w = vv[j].w * dd;
                O4[i + 64] = o;
            }
            dd *= step;
        }
    }
    __syncthreads();

    // ---- column stats: thread t = column d ---------------------------------
    {
        const float* S = (const float*)stor4;
        float cm = 0.f, s1 = 0.f, s2 = 0.f;
        #pragma unroll
        for (int k = 0; k < K_N; ++k){
            float m = mask_s[k];
            float x = S[k*D_N + t];
            cm += m; s1 += m*x; s2 += m*x*x;
        }
        float denom = cm + 1e-8f;
        float mu = s1 / denom;
        float var = (s2 - 2.0f*mu*s1 + mu*mu*cm) / denom;
        float sd = sqrtf(fmaxf(var, 0.0f));
        mu_s[t] = mu;
        float z = fabsf((nm_s[t] - mu) / (sd + 1e-8f));
        unsigned long long bal = __ballot(z > 2.0f);
        if (lane == 0) zc_s[h] = __popcll(bal);
    }
    __syncthreads();

    // ---- coalesced matvec: wave h covers k in [64h, 64h+64) ----------------
    // lane l accumulates outputs j = 4l..4l+3; w1bT[k][j] lane-contiguous.
    float pre1a = bf2f(cat1[(long)b*640 + 384 + t]);     // pre1a (incl imp_b1)
    {
        float ax = 0.f, ay = 0.f, az = 0.f, aw = 0.f;
        const bf16* wp = w1bT + (long)(h*64)*256 + 4*lane;
        #pragma unroll 4
        for (int s = 0; s < 64; ++s){
            ushort4 wv = *(const ushort4*)(wp + s*256);
            float m = mu_s[h*64 + s];
            ax += m * bfb2f((short)wv.x);
            ay += m * bfb2f((short)wv.y);
            az += m * bfb2f((short)wv.z);
            aw += m * bfb2f((short)wv.w);
        }
        float4 a4; a4.x = ax; a4.y = ay; a4.z = az; a4.w = aw;
        ((float4*)redm)[h*64 + lane] = a4;
    }
    __syncthreads();

    // ---- t[j] = relu(pre1a + sum_w redm); imp & learned partials -----------
    {
        float acc = pre1a + redm[t] + redm[256+t] + redm[512+t] + redm[768+t];
        float tj = fmaxf(acc, 0.0f);
        float pi = tj * imp_w2[t];
        float pl = (t < 128) ? bf2f(cat1[(long)b*640 + t]) * ad_w2[t] : 0.0f;
        #pragma unroll
        for (int s = 32; s; s >>= 1){ pi += __shfl_xor(pi, s); pl += __shfl_xor(pl, s); }
        if (lane == 0){ red_s[h] = pi; red_s[H_N + h] = pl; }
    }
    __syncthreads();

    float impv;
    {
        float p  = red_s[0]+red_s[1]+red_s[2]+red_s[3] + imp_b2[0];
        float plr= red_s[4]+red_s[5]+red_s[6]+red_s[7] + ad_b2[0];
        float learned = 1.0f / (1.0f + expf(-plr));
        float stat = (float)(zc_s[0]+zc_s[1]+zc_s[2]+zc_s[3]) * (1.0f/256.0f);
        float sp = (p > 20.0f) ? p : log1pf(expf(p));
        impv = sp * (1.0f + 0.5f*stat + 0.5f*learned);
    }
    if (h == 0){                              // st row 0 = imp * nm
        float4 o;
        o.x = impv * nm4.x; o.y = impv * nm4.y;
        o.z = impv * nm4.z; o.w = impv * nm4.w;
        O4[lane] = o;
    }

    // ---- scores: 21 partials, one batched shuffle reduce -------------------
    short4 r4  = ((const short4*)(R_bf + (long)b * (H_N*D_N) + h * D_N))[lane];
    float4 R4;
    R4.x = bfb2f(r4.x); R4.y = bfb2f(r4.y); R4.z = bfb2f(r4.z); R4.w = bfb2f(r4.w);
    float4 g4 = ((const float4*)(g + h * D_N))[lane];

    const int NP = K_N + 1;                   // [0]=nm.g, [1]=nm.R, [2+k]=row k.R
    float p[NP];
    p[0] = nm4.x*g4.x + nm4.y*g4.y + nm4.z*g4.z + nm4.w*g4.w;
    p[1] = nm4.x*R4.x + nm4.y*R4.y + nm4.z*R4.z + nm4.w*R4.w;
    #pragma unroll
    for (int k = 0; k < K_N-1; ++k){
        float4 x = stor4[k*64 + lane];
        p[2+k] = x.x*R4.x + x.y*R4.y + x.z*R4.z + x.w*R4.w;
    }
    #pragma unroll
    for (int s = 32; s; s >>= 1){
        #pragma unroll
        for (int j = 0; j < NP; ++j) p[j] += __shfl_xor(p[j], s);
    }
    float qb = p[0] + qc[h];
    float s0 = (impv * p[1] + qb) * 0.125f;   // in-place: p[2+k] -> score -> weight
    float mx = s0;
    {
        float dd = 1.0f;
        #pragma unroll
        for (int k = 0; k < K_N-1; ++k){
            p[2+k] = (dd * p[2+k] + qb) * 0.125f;
            mx = fmaxf(mx, p[2+k]);
            dd *= 0.95f;
        }
    }
    float w0 = expf(s0 - mx);
    float l = w0;
    #pragma unroll
    for (int k = 0; k < K_N-1; ++k){ p[2+k] = expf(p[2+k] - mx); l += p[2+k]; }
    float inv = 1.0f / l;
    w0 *= inv * impv;

    // ---- u = w0*nm + sum_k (p[2+k]*inv*dec_k)*storage[k] -------------------
    float4 acc;
    acc.x = w0 * nm4.x; acc.y = w0 * nm4.y; acc.z = w0 * nm4.z; acc.w = w0 * nm4.w;
    {
        float dd = inv;
        #pragma unroll
        for (int k = 0; k < K_N-1; ++k){
            float c = p[2+k] * dd;
            float4 x = stor4[k*64 + lane];
            acc.x += c*x.x; acc.y += c*x.y; acc.z += c*x.z; acc.w += c*x.w;
            dd *= 0.95f;
        }
    }
    short4 us;
    us.x = bfbits(acc.x); us.y = bfbits(acc.y); us.z = bfbits(acc.z); us.w = bfbits(acc.w);
    ((short4*)(u_bf + (long)b * (H_N*D_N) + h * D_N))[lane] = us;
}

// ---------------------------------------------------------------- launch ----
extern "C" void kernel_launch(void* const* d_in, const int* in_sizes, int n_in,
                              void* d_out, int out_size, void* d_ws, size_t ws_size,
                              hipStream_t stream)
{
    (void)in_sizes; (void)n_in; (void)out_size; (void)ws_size;
    const float* storage    = (const float*)d_in[0];
    const float* nm         = (const float*)d_in[1];
    const float* ad_w1      = (const float*)d_in[2];
    const float* ad_b1      = (const float*)d_in[3];
    const float* ad_w2      = (const float*)d_in[4];
    const float* ad_b2      = (const float*)d_in[5];
    const float* imp_w1     = (const float*)d_in[6];
    const float* imp_b1     = (const float*)d_in[7];
    const float* imp_w2     = (const float*)d_in[8];
    const float* imp_b2     = (const float*)d_in[9];
    const float* attn_in_w  = (const float*)d_in[10];
    const float* attn_in_b  = (const float*)d_in[11];
    const float* attn_out_w = (const float*)d_in[12];
    const float* attn_out_b = (const float*)d_in[13];

    char* p = (char*)d_ws;
    auto alloc = [&](size_t bytes)->char*{ char* r = p; p += (bytes + 255) & ~(size_t)255; return r; };
    bf16*  attn_bf   = (bf16*) alloc((size_t)768*256*2);
    bf16*  w1bT      = (bf16*) alloc((size_t)256*256*2);
    bf16*  wout_bf   = (bf16*) alloc((size_t)256*256*2);
    bf16*  wcat      = (bf16*) alloc((size_t)640*256*2);
    float* catb      = (float*)alloc((size_t)640*4);
    float* g         = (float*)alloc((size_t)1024*4);
    float* qc        = (float*)alloc((size_t)4*4);
    bf16*  wkT       = (bf16*) alloc((size_t)1024*64*2);
    bf16*  nm_bf     = (bf16*) alloc((size_t)B_N*256*2);
    bf16*  cat1      = (bf16*) alloc((size_t)B_N*640*2);
    bf16*  R_bf      = (bf16*) alloc((size_t)B_N*1024*2);
    bf16*  u_bf      = (bf16*) alloc((size_t)B_N*1024*2);
    bf16*  ctx_bf    = (bf16*) alloc((size_t)B_N*256*2);

    float* st_out  = (float*)d_out;
    float* agg_out = (float*)d_out + (size_t)B_N * K_N * D_N;

    // 1. prep
    {
        long total = 768*256 + 65536 + 256*256 + 640*256 + 640 + 1024 + 4 + 1024*64 + (long)B_N*256;
        int grid = (int)((total + 255) / 256);
        k_prep<<<grid, 256, 0, stream>>>(ad_w1, ad_b1, imp_w1, imp_b1, attn_in_w, attn_in_b,
                                         attn_out_w, nm, attn_bf, w1bT, wout_bf, wcat, catb,
                                         g, qc, wkT, nm_bf);
    }
    // 2. fused nm GEMM: cols [0,128)=relu(ad) | [128,384)=q+bq | [384,640)=pre1a+imp_b1
    k_gemm<<<dim3(B_N/64, 640/64), 256, 0, stream>>>(nm_bf, 256, 30, 0, wcat, 256, catb,
        (const bf16*)nullptr, 0, cat1, 640, 1, 128, 256);
    // 3. R = q_h @ wk_h  (K=64, per-head A offset, wkT rows contiguous in k)
    k_gemm<<<dim3(B_N/64, 1024/64), 256, 0, stream>>>(cat1 + 128, 640, 8, 64, wkT, 64,
        (const float*)nullptr, (const bf16*)nullptr, 0, R_bf, 1024, 1, 0, 64);
    // 4. fused stats + anomaly + importance + attention + st/u write
    k_fused<<<B_N, 256, 0, stream>>>(storage, nm, R_bf, cat1, w1bT,
        ad_w2, ad_b2, imp_w2, imp_b2, g, qc, st_out, u_bf);
    // 5. ctx_head = u_head @ wv^T + bv   (per-64-col A group)
    k_gemm<<<dim3(B_N/64, 256/64), 256, 0, stream>>>(u_bf, 1024, 6, 256, attn_bf + 512*256, 256,
        attn_in_b + 512, (const bf16*)nullptr, 0, ctx_bf, 256, 1, 0, 256);
    // 6. agg = ctx @ Wout^T + bout  (fp32 out)
    k_gemm<<<dim3(B_N/64, 256/64), 256, 0, stream>>>(ctx_bf, 256, 30, 0, wout_bf, 256,
        attn_out_b, (const bf16*)nullptr, 0, agg_out, 256, 0, 0, 256);
}